// Round 3
// baseline (458.078 us; speedup 1.0000x reference)
//
#include <hip/hip_runtime.h>
#include <hip/hip_bf16.h>
#include <math.h>

#define NE 32        // experts
#define H 512
#define H2 1024      // 2H
#define NTOK 2048    // B*S
#define CAP 2048     // per-expert token capacity (worst case)
#define MAXTILES 96  // sum_e ceil(cnt_e/128) <= 32 + 8192/128 = 96
#define TSTRIDE 144  // transpose-buffer row stride (ushorts): 288 B -> quads hit
                     // disjoint bank octets (288/4 mod 32 = 8), 16B-aligned

typedef __attribute__((ext_vector_type(8))) short bf16x8;
typedef __attribute__((ext_vector_type(4))) float f32x4;
typedef unsigned int uint;
typedef unsigned short ushort;

__device__ __forceinline__ uint bf16r(float f) {
    uint u = __float_as_uint(f);
    return (u + 0x7FFFu + ((u >> 16) & 1u)) >> 16;   // RNE
}
__device__ __forceinline__ uint pack_bf16(float a, float b) {
    return bf16r(a) | (bf16r(b) << 16);
}
__device__ __forceinline__ float bf16f(ushort u) {
    return __uint_as_float(((uint)u) << 16);
}

// ---------------------------------------------------------------------------
// Kernel 1: gating — logits, softmax, top-4, renorm, expert lists, x->bf16
// one wave per token; block=256 (4 tokens), grid = NTOK/4
// ---------------------------------------------------------------------------
__global__ __launch_bounds__(256) void gating_kernel(
    const float* __restrict__ x, const float* __restrict__ gate_w,
    int* __restrict__ cnt, int* __restrict__ listTok, int* __restrict__ listPair,
    float* __restrict__ listW, ushort* __restrict__ xbf)
{
    const int wave = threadIdx.x >> 6;
    const int lane = threadIdx.x & 63;
    const int t = blockIdx.x * 4 + wave;
    const int e = lane & 31;
    const int half = lane >> 5;

    const float4* xr = (const float4*)(x + (size_t)t * H + half * 256);
    const float4* gr = (const float4*)(gate_w + (size_t)e * H + half * 256);
    float acc = 0.f;
#pragma unroll 8
    for (int i = 0; i < 64; ++i) {
        float4 a = xr[i], b = gr[i];
        acc += a.x * b.x + a.y * b.y + a.z * b.z + a.w * b.w;
    }
    acc += __shfl_xor(acc, 32);   // combine halves: all lanes hold logit[e]

    // softmax over 32 experts (duplicated across lane groups)
    float mx = acc;
#pragma unroll
    for (int m = 16; m >= 1; m >>= 1) mx = fmaxf(mx, __shfl_xor(mx, m));
    float p = __expf(acc - mx);
    float s = p;
#pragma unroll
    for (int m = 16; m >= 1; m >>= 1) s += __shfl_xor(s, m);
    float prob = p / s;

    // top-4 (ties -> lowest index, matches lax.top_k)
    int   selk[4];
    float wk[4];
    float sum4 = 0.f;
#pragma unroll
    for (int k = 0; k < 4; ++k) {
        float v = prob; int idx = e;
#pragma unroll
        for (int m = 16; m >= 1; m >>= 1) {
            float v2 = __shfl_xor(v, m);
            int   i2 = __shfl_xor(idx, m);
            if (v2 > v || (v2 == v && i2 < idx)) { v = v2; idx = i2; }
        }
        selk[k] = idx; wk[k] = v; sum4 += v;
        if (e == idx) prob = -1.f;
    }

    if (lane == 0) {
#pragma unroll
        for (int k = 0; k < 4; ++k) {
            int ex = selk[k];
            int pos = atomicAdd(&cnt[ex], 1);
            listTok [ex * CAP + pos] = t;
            listPair[ex * CAP + pos] = t * 4 + k;
            listW   [ex * CAP + pos] = wk[k] / sum4;
        }
    }

    // convert this token's x row to bf16 (8 elems per lane)
    const float4* xrow4 = (const float4*)(x + (size_t)t * H);
    float4 a0 = xrow4[lane * 2];
    float4 a1 = xrow4[lane * 2 + 1];
    uint4 o;
    o.x = pack_bf16(a0.x, a0.y);
    o.y = pack_bf16(a0.z, a0.w);
    o.z = pack_bf16(a1.x, a1.y);
    o.w = pack_bf16(a1.z, a1.w);
    ((uint4*)(xbf + (size_t)t * H))[lane] = o;
}

// ---------------------------------------------------------------------------
// Kernel 1b: scheduler — build dense (expert, mtile) worklist. 1 wave.
// ---------------------------------------------------------------------------
__global__ void sched_kernel(const int* __restrict__ cnt,
                             int* __restrict__ ntiles, int* __restrict__ desc)
{
    const int lane = threadIdx.x;
    int t = 0;
    if (lane < NE) t = (cnt[lane] + 127) >> 7;
    int pre = t;
#pragma unroll
    for (int m = 1; m < 64; m <<= 1) {
        int v = __shfl_up(pre, m);
        if (lane >= m) pre += v;
    }
    const int off = pre - t;   // exclusive prefix
    if (lane < NE)
        for (int i = 0; i < t; ++i) desc[off + i] = (lane << 16) | i;
    if (lane == 63) *ntiles = pre;
}

// ---------------------------------------------------------------------------
// K-loop LDS layout: 128 rows x 64 ushorts as 8 chunks/row of 16 B,
// chunk slot = c ^ (r & 7). No padding, 16 KB per buffer.
// ---------------------------------------------------------------------------
__device__ __forceinline__ int lds_chunk(int r, int c) {
    return r * 8 + (c ^ (r & 7));
}

// ---------------------------------------------------------------------------
// Kernel 2: grouped GEMM1 + SiLU*up, scaled by combine weight.
// item = tile*8 + ch; tile -> (e, mt of 128 rows); ch -> 128 cols of 2H
// hidden[pair][2H] (bf16) = silu(X@wg^T) * (X@wu^T) * w_pair
// ---------------------------------------------------------------------------
__global__ __launch_bounds__(256, 3) void moe_gemm1(
    const float* __restrict__ w_gate, const float* __restrict__ w_up,
    const ushort* __restrict__ xbf, const int* __restrict__ cnt,
    const int* __restrict__ listTok, const int* __restrict__ listPair,
    const float* __restrict__ listW, ushort* __restrict__ hidden,
    const int* __restrict__ ntiles, const int* __restrict__ desc)
{
    const int item = blockIdx.x;
    if (item >= (*ntiles) * 8) return;
    const int d  = desc[item >> 3];
    const int ch = item & 7;
    const int e  = d >> 16;
    const int mt = d & 0xffff;
    const int count = cnt[e];
    const int m0 = mt * 128;

    __shared__ ushort smem[3 * 128 * 64];   // 48 KB; also epilogue transpose
    ushort* Xs = smem;
    ushort* Gs = smem + 128 * 64;
    ushort* Us = smem + 2 * 128 * 64;

    const int tid  = threadIdx.x;
    const int lane = tid & 63;
    const int wave = tid >> 6;
    const int l15  = lane & 15;
    const int quad = lane >> 4;

    // staging map: 2 threads per row, 32 elems (4 chunks) each
    const int sr = tid >> 1;
    const int sh = tid & 1;
    const int slot = m0 + sr;
    const int tok  = (slot < count) ? listTok[e * CAP + slot] : 0;
    const ushort* xrow = xbf + (size_t)tok * H;
    const float*  grow = w_gate + ((size_t)e * H2 + (size_t)(ch * 128 + sr)) * H;
    const float*  urow = w_up   + ((size_t)e * H2 + (size_t)(ch * 128 + sr)) * H;

    f32x4 accg[2][8], accu[2][8];
    const f32x4 fz = {0.f, 0.f, 0.f, 0.f};
#pragma unroll
    for (int mi = 0; mi < 2; ++mi)
#pragma unroll
        for (int ni = 0; ni < 8; ++ni) { accg[mi][ni] = fz; accu[mi][ni] = fz; }

    for (int k0 = 0; k0 < H; k0 += 64) {
        const uint4* xs = (const uint4*)(xrow + k0 + sh * 32);
        uint4 xv[4];
#pragma unroll
        for (int i = 0; i < 4; ++i) xv[i] = xs[i];
        const float4* gp = (const float4*)(grow + k0 + sh * 32);
        const float4* up = (const float4*)(urow + k0 + sh * 32);
        float4 g[8], u[8];
#pragma unroll
        for (int i = 0; i < 8; ++i) { g[i] = gp[i]; u[i] = up[i]; }

        __syncthreads();   // previous iter's LDS reads done

        uint4* xl = (uint4*)Xs;
        uint4* gl = (uint4*)Gs;
        uint4* ul = (uint4*)Us;
#pragma unroll
        for (int i = 0; i < 4; ++i) {
            const int cs = lds_chunk(sr, sh * 4 + i);
            xl[cs] = xv[i];
            uint4 w;
            w.x = pack_bf16(g[2*i].x,   g[2*i].y);
            w.y = pack_bf16(g[2*i].z,   g[2*i].w);
            w.z = pack_bf16(g[2*i+1].x, g[2*i+1].y);
            w.w = pack_bf16(g[2*i+1].z, g[2*i+1].w);
            gl[cs] = w;
            uint4 v;
            v.x = pack_bf16(u[2*i].x,   u[2*i].y);
            v.y = pack_bf16(u[2*i].z,   u[2*i].w);
            v.z = pack_bf16(u[2*i+1].x, u[2*i+1].y);
            v.w = pack_bf16(u[2*i+1].z, u[2*i+1].w);
            ul[cs] = v;
        }
        __syncthreads();

#pragma unroll
        for (int ks = 0; ks < 2; ++ks) {
            const int cc = ks * 4 + quad;
            bf16x8 af[2];
            af[0] = *(const bf16x8*)((const uint4*)Xs + lds_chunk(wave * 32 +      l15, cc));
            af[1] = *(const bf16x8*)((const uint4*)Xs + lds_chunk(wave * 32 + 16 + l15, cc));
#pragma unroll
            for (int ni = 0; ni < 8; ++ni) {
                bf16x8 bg = *(const bf16x8*)((const uint4*)Gs + lds_chunk(ni * 16 + l15, cc));
                bf16x8 bu = *(const bf16x8*)((const uint4*)Us + lds_chunk(ni * 16 + l15, cc));
                accg[0][ni] = __builtin_amdgcn_mfma_f32_16x16x32_bf16(af[0], bg, accg[0][ni], 0, 0, 0);
                accg[1][ni] = __builtin_amdgcn_mfma_f32_16x16x32_bf16(af[1], bg, accg[1][ni], 0, 0, 0);
                accu[0][ni] = __builtin_amdgcn_mfma_f32_16x16x32_bf16(af[0], bu, accu[0][ni], 0, 0, 0);
                accu[1][ni] = __builtin_amdgcn_mfma_f32_16x16x32_bf16(af[1], bu, accu[1][ni], 0, 0, 0);
            }
        }
    }

    // epilogue: hidden = silu(g)*u * w_pair -> LDS transpose -> coalesced store
    __syncthreads();
    ushort* T = smem;
#pragma unroll
    for (int mi = 0; mi < 2; ++mi) {
        const int mrow = wave * 32 + mi * 16 + quad * 4;
#pragma unroll
        for (int r = 0; r < 4; ++r) {
            const int slot2 = m0 + mrow + r;
            const float wgt = (slot2 < count) ? listW[e * CAP + slot2] : 0.f;
#pragma unroll
            for (int ni = 0; ni < 8; ++ni) {
                float gv = accg[mi][ni][r];
                float uv = accu[mi][ni][r];
                float hv = (gv / (1.f + __expf(-gv))) * uv * wgt;
                T[(mrow + r) * TSTRIDE + ni * 16 + l15] = (ushort)bf16r(hv);
            }
        }
    }
    __syncthreads();
    {
        const int row = tid >> 1;
        const int half = tid & 1;
        const int slot2 = m0 + row;
        if (slot2 < count) {
            const int pr = listPair[e * CAP + slot2];
            uint4* dst = (uint4*)(hidden + (size_t)pr * H2 + ch * 128 + half * 64);
            const uint4* src = (const uint4*)(T + row * TSTRIDE + half * 64);
#pragma unroll
            for (int i = 0; i < 8; ++i) dst[i] = src[i];
        }
    }
}

// ---------------------------------------------------------------------------
// Kernel 3: grouped GEMM2: pairOut[split][pair] = hidden[pair][Kslice] @ wd^T
// item = tile*8 + split*4 + ch; no atomics; bf16 partials, coalesced stores.
// ---------------------------------------------------------------------------
__global__ __launch_bounds__(256, 3) void moe_gemm2(
    const float* __restrict__ w_down, const ushort* __restrict__ hidden,
    const int* __restrict__ cnt, const int* __restrict__ listTok,
    const int* __restrict__ listPair, ushort* __restrict__ pairOut,
    const int* __restrict__ ntiles, const int* __restrict__ desc)
{
    const int item = blockIdx.x;
    if (item >= (*ntiles) * 8) return;
    const int d   = desc[item >> 3];
    const int ks2 = (item >> 2) & 1;   // K split
    const int ch  = item & 3;
    const int e   = d >> 16;
    const int mt  = d & 0xffff;
    const int count = cnt[e];
    const int m0 = mt * 128;

    __shared__ ushort smem[128 * TSTRIDE];  // 36 KB; holds As+Bs, then transpose
    ushort* As = smem;
    ushort* Bs = smem + 128 * 64;

    const int tid  = threadIdx.x;
    const int lane = tid & 63;
    const int wave = tid >> 6;
    const int l15  = lane & 15;
    const int quad = lane >> 4;

    const int sr = tid >> 1;
    const int sh = tid & 1;
    const int slot = m0 + sr;
    const int pr0 = (slot < count) ? listPair[e * CAP + slot] : 0;
    const ushort* arow = hidden + (size_t)pr0 * H2 + ks2 * 512;
    const float*  brow = w_down + ((size_t)e * H + (size_t)(ch * 128 + sr)) * H2 + ks2 * 512;

    f32x4 acc[2][8];
    const f32x4 fz = {0.f, 0.f, 0.f, 0.f};
#pragma unroll
    for (int mi = 0; mi < 2; ++mi)
#pragma unroll
        for (int ni = 0; ni < 8; ++ni) acc[mi][ni] = fz;

    for (int k0 = 0; k0 < 512; k0 += 64) {
        const uint4* ap = (const uint4*)(arow + k0 + sh * 32);
        uint4 av[4];
#pragma unroll
        for (int i = 0; i < 4; ++i) av[i] = ap[i];
        const float4* bp = (const float4*)(brow + k0 + sh * 32);
        float4 b[8];
#pragma unroll
        for (int i = 0; i < 8; ++i) b[i] = bp[i];

        __syncthreads();

        uint4* al = (uint4*)As;
        uint4* bl = (uint4*)Bs;
#pragma unroll
        for (int i = 0; i < 4; ++i) {
            const int cs = lds_chunk(sr, sh * 4 + i);
            al[cs] = av[i];
            uint4 w;
            w.x = pack_bf16(b[2*i].x,   b[2*i].y);
            w.y = pack_bf16(b[2*i].z,   b[2*i].w);
            w.z = pack_bf16(b[2*i+1].x, b[2*i+1].y);
            w.w = pack_bf16(b[2*i+1].z, b[2*i+1].w);
            bl[cs] = w;
        }
        __syncthreads();

#pragma unroll
        for (int ks = 0; ks < 2; ++ks) {
            const int cc = ks * 4 + quad;
            bf16x8 af[2];
            af[0] = *(const bf16x8*)((const uint4*)As + lds_chunk(wave * 32 +      l15, cc));
            af[1] = *(const bf16x8*)((const uint4*)As + lds_chunk(wave * 32 + 16 + l15, cc));
#pragma unroll
            for (int ni = 0; ni < 8; ++ni) {
                bf16x8 bf = *(const bf16x8*)((const uint4*)Bs + lds_chunk(ni * 16 + l15, cc));
                acc[0][ni] = __builtin_amdgcn_mfma_f32_16x16x32_bf16(af[0], bf, acc[0][ni], 0, 0, 0);
                acc[1][ni] = __builtin_amdgcn_mfma_f32_16x16x32_bf16(af[1], bf, acc[1][ni], 0, 0, 0);
            }
        }
    }

    // epilogue: LDS transpose -> coalesced bf16 stores to pairOut
    __syncthreads();
    ushort* T = smem;
#pragma unroll
    for (int mi = 0; mi < 2; ++mi) {
        const int mrow = wave * 32 + mi * 16 + quad * 4;
#pragma unroll
        for (int r = 0; r < 4; ++r) {
#pragma unroll
            for (int ni = 0; ni < 8; ++ni) {
                T[(mrow + r) * TSTRIDE + ni * 16 + l15] = (ushort)bf16r(acc[mi][ni][r]);
            }
        }
    }
    __syncthreads();
    {
        const int row = tid >> 1;
        const int half = tid & 1;
        const int slot2 = m0 + row;
        if (slot2 < count) {
            const int pr = listPair[e * CAP + slot2];
            uint4* dst = (uint4*)(pairOut + ((size_t)(ks2 << 13) + pr) * H + ch * 128 + half * 64);
            const uint4* src = (const uint4*)(T + row * TSTRIDE + half * 64);
#pragma unroll
            for (int i = 0; i < 8; ++i) dst[i] = src[i];
        }
    }
}

// ---------------------------------------------------------------------------
// Kernel 4: combine — out[t][c] = sum over k(4) x split(2) of pairOut rows.
// Fully overwrites d_out (no memset needed). grid 512 x 256.
// ---------------------------------------------------------------------------
__global__ __launch_bounds__(256) void combine_kernel(
    const ushort* __restrict__ pairOut, float* __restrict__ out)
{
    const int tok = blockIdx.x * 4 + (threadIdx.x >> 6);
    const int c   = (threadIdx.x & 63) * 8;
    float s[8];
#pragma unroll
    for (int i = 0; i < 8; ++i) s[i] = 0.f;
#pragma unroll
    for (int j = 0; j < 8; ++j) {
        const int row = ((j & 1) << 13) + tok * 4 + (j >> 1);
        uint4 v = *(const uint4*)(pairOut + (size_t)row * H + c);
        const ushort* u = (const ushort*)&v;
#pragma unroll
        for (int i = 0; i < 8; ++i) s[i] += bf16f(u[i]);
    }
    float4* o = (float4*)(out + (size_t)tok * H + c);
    o[0] = make_float4(s[0], s[1], s[2], s[3]);
    o[1] = make_float4(s[4], s[5], s[6], s[7]);
}

// ---------------------------------------------------------------------------
extern "C" void kernel_launch(void* const* d_in, const int* in_sizes, int n_in,
                              void* d_out, int out_size, void* d_ws, size_t ws_size,
                              hipStream_t stream)
{
    (void)in_sizes; (void)n_in; (void)ws_size; (void)out_size;
    const float* x      = (const float*)d_in[0];
    const float* gate_w = (const float*)d_in[1];
    const float* w_gate = (const float*)d_in[2];
    const float* w_up   = (const float*)d_in[3];
    const float* w_down = (const float*)d_in[4];

    char* ws = (char*)d_ws;
    int*    cnt      = (int*)ws;                       // 32 ints
    int*    ntiles   = (int*)(ws + 128);
    int*    desc     = (int*)(ws + 256);               // MAXTILES ints
    char*   dyn      = ws + 1024;
    int*    listTok  = (int*)dyn;                                   // 256 KB
    int*    listPair = (int*)(dyn + (size_t)NE * CAP * 4);          // 256 KB
    float*  listW    = (float*)(dyn + (size_t)NE * CAP * 8);        // 256 KB
    ushort* xbf      = (ushort*)(dyn + (size_t)NE * CAP * 12);      // 2 MB
    ushort* hidden   = (ushort*)(dyn + (size_t)NE * CAP * 12
                                 + (size_t)NTOK * H * 2);           // 16 MB
    ushort* pairOut  = (ushort*)(dyn + (size_t)NE * CAP * 12
                                 + (size_t)NTOK * H * 2
                                 + (size_t)NTOK * 4 * H2 * 2);      // 16 MB

    hipMemsetAsync(ws, 0, 256, stream);

    gating_kernel<<<NTOK / 4, 256, 0, stream>>>(x, gate_w, cnt, listTok, listPair, listW, xbf);
    sched_kernel<<<1, 64, 0, stream>>>(cnt, ntiles, desc);
    moe_gemm1<<<MAXTILES * 8, 256, 0, stream>>>(w_gate, w_up, xbf, cnt, listTok,
                                                listPair, listW, hidden, ntiles, desc);
    moe_gemm2<<<MAXTILES * 8, 256, 0, stream>>>(w_down, hidden, cnt, listTok,
                                                listPair, pairOut, ntiles, desc);
    combine_kernel<<<NTOK / 4, 256, 0, stream>>>(pairOut, (float*)d_out);
}

// Round 5
// 333.387 us; speedup vs baseline: 1.3740x; 1.3740x over previous
//
#include <hip/hip_runtime.h>
#include <hip/hip_bf16.h>
#include <math.h>

#define NE 32        // experts
#define H 512
#define H2 1024      // 2H
#define NTOK 2048    // B*S
#define CAP 2048     // per-expert token capacity (worst case)
#define BM 64        // M-tile (tokens per block)
#define MAXT64 160   // sum_e ceil(cnt_e/64) <= 32 + 8192/64 = 160
#define TSTRIDE 144  // epilogue transpose row stride (ushorts)

typedef __attribute__((ext_vector_type(8))) short bf16x8;
typedef __attribute__((ext_vector_type(4))) float f32x4;
typedef unsigned int uint;
typedef unsigned short ushort;

__device__ __forceinline__ uint bf16r(float f) {
    uint u = __float_as_uint(f);
    return (u + 0x7FFFu + ((u >> 16) & 1u)) >> 16;   // RNE
}
__device__ __forceinline__ uint pack_bf16(float a, float b) {
    return bf16r(a) | (bf16r(b) << 16);
}
__device__ __forceinline__ float bf16f(ushort u) {
    return __uint_as_float(((uint)u) << 16);
}

// async 16-B global->LDS DMA; LDS dest is wave-uniform base + lane*16
__device__ __forceinline__ void dma16(const void* g, void* l) {
    __builtin_amdgcn_global_load_lds(
        (const __attribute__((address_space(1))) uint*)g,
        (__attribute__((address_space(3))) uint*)l, 16, 0, 0);
}

// ---------------------------------------------------------------------------
// Kernel 1: prep = gating (blocks 0..511) + weight fp32->bf16 convert (rest).
// ---------------------------------------------------------------------------
__global__ __launch_bounds__(256) void prep_kernel(
    const float* __restrict__ x, const float* __restrict__ gate_w,
    int* __restrict__ cnt, int* __restrict__ listTok, int* __restrict__ listPair,
    float* __restrict__ listW, ushort* __restrict__ xbf,
    const float* __restrict__ wg, const float* __restrict__ wu,
    const float* __restrict__ wd,
    ushort* __restrict__ wgb, ushort* __restrict__ wub, ushort* __restrict__ wdb)
{
    const int b = blockIdx.x;
    if (b >= 512) {
        const int b2 = b - 512;
        const float* src = (b2 < 8192) ? wg : (b2 < 16384) ? wu : wd;
        ushort*     dst  = (b2 < 8192) ? wgb : (b2 < 16384) ? wub : wdb;
        const size_t base = (size_t)(b2 & 8191) * 2048 + (size_t)threadIdx.x * 8;
        const float4* s = (const float4*)(src + base);
        float4 x0 = s[0], x1 = s[1];
        uint4 v;
        v.x = pack_bf16(x0.x, x0.y); v.y = pack_bf16(x0.z, x0.w);
        v.z = pack_bf16(x1.x, x1.y); v.w = pack_bf16(x1.z, x1.w);
        *(uint4*)(dst + base) = v;
        return;
    }

    const int wave = threadIdx.x >> 6;
    const int lane = threadIdx.x & 63;
    const int t = b * 4 + wave;
    const int e = lane & 31;
    const int half = lane >> 5;

    const float4* xr = (const float4*)(x + (size_t)t * H + half * 256);
    const float4* gr = (const float4*)(gate_w + (size_t)e * H + half * 256);
    float acc = 0.f;
#pragma unroll 8
    for (int i = 0; i < 64; ++i) {
        float4 a = xr[i], g = gr[i];
        acc += a.x * g.x + a.y * g.y + a.z * g.z + a.w * g.w;
    }
    acc += __shfl_xor(acc, 32);

    float mx = acc;
#pragma unroll
    for (int m = 16; m >= 1; m >>= 1) mx = fmaxf(mx, __shfl_xor(mx, m));
    float p = __expf(acc - mx);
    float s = p;
#pragma unroll
    for (int m = 16; m >= 1; m >>= 1) s += __shfl_xor(s, m);
    float prob = p / s;

    int selk[4]; float wk[4]; float sum4 = 0.f;
#pragma unroll
    for (int k = 0; k < 4; ++k) {
        float v = prob; int idx = e;
#pragma unroll
        for (int m = 16; m >= 1; m >>= 1) {
            float v2 = __shfl_xor(v, m);
            int   i2 = __shfl_xor(idx, m);
            if (v2 > v || (v2 == v && i2 < idx)) { v = v2; idx = i2; }
        }
        selk[k] = idx; wk[k] = v; sum4 += v;
        if (e == idx) prob = -1.f;
    }

    if (lane == 0) {
#pragma unroll
        for (int k = 0; k < 4; ++k) {
            int ex = selk[k];
            int pos = atomicAdd(&cnt[ex], 1);
            listTok [ex * CAP + pos] = t;
            listPair[ex * CAP + pos] = t * 4 + k;
            listW   [ex * CAP + pos] = wk[k] / sum4;
        }
    }

    const float4* xrow4 = (const float4*)(x + (size_t)t * H);
    float4 a0 = xrow4[lane * 2];
    float4 a1 = xrow4[lane * 2 + 1];
    uint4 o;
    o.x = pack_bf16(a0.x, a0.y); o.y = pack_bf16(a0.z, a0.w);
    o.z = pack_bf16(a1.x, a1.y); o.w = pack_bf16(a1.z, a1.w);
    ((uint4*)(xbf + (size_t)t * H))[lane] = o;
}

// ---------------------------------------------------------------------------
// Kernel 1b: scheduler — dense (expert, mtile64) worklist. 1 wave.
// ---------------------------------------------------------------------------
__global__ void sched_kernel(const int* __restrict__ cnt,
                             int* __restrict__ ntiles, int* __restrict__ desc)
{
    const int lane = threadIdx.x;
    int t = 0;
    if (lane < NE) t = (cnt[lane] + 63) >> 6;
    int pre = t;
#pragma unroll
    for (int m = 1; m < 64; m <<= 1) {
        int v = __shfl_up(pre, m);
        if (lane >= m) pre += v;
    }
    const int off = pre - t;
    if (lane < NE)
        for (int i = 0; i < t; ++i) desc[off + i] = (lane << 16) | i;
    if (lane == 63) *ntiles = pre;
}

// ---------------------------------------------------------------------------
// Kernel 2: grouped GEMM1 + SiLU*up, scaled by combine weight.
// item = tile*8 + ch; tile -> (e, 64 tokens); ch -> 128 cols of 2H.
// ---------------------------------------------------------------------------
template<bool WB>
__global__ __launch_bounds__(256, 4) void moe_gemm1(
    const void* __restrict__ wgate_, const void* __restrict__ wup_,
    const ushort* __restrict__ xbf, const int* __restrict__ cnt,
    const int* __restrict__ listTok, const int* __restrict__ listPair,
    const float* __restrict__ listW, ushort* __restrict__ hidden,
    const int* __restrict__ ntiles, const int* __restrict__ desc)
{
    const int item = blockIdx.x;
    if (item >= (*ntiles) * 8) return;
    const int d  = desc[item >> 3];
    const int ch = item & 7;
    const int e  = d >> 16;
    const int mt = d & 0xffff;
    const int count = cnt[e];
    const int m0 = mt * BM;

    __shared__ ushort smem[2 * 128 * 64];   // 32 KB: Gs | Us; epilogue T overlays
    ushort* Gs = smem;
    ushort* Us = smem + 128 * 64;

    const int tid  = threadIdx.x;
    const int lane = tid & 63;
    const int w    = tid >> 6;
    const int l15  = lane & 15;
    const int quad = lane >> 4;

    // A row (token) for this lane
    const int arow = m0 + w * 16 + l15;
    const int atok = (arow < count) ? listTok[e * CAP + arow] : 0;
    const char* aptr = (const char*)(xbf + (size_t)atok * H);

    // bf16 DMA staging coords: lane -> (row w*32 + i*8 + rr, piece p^rr)
    const int rr = lane >> 3;   // 0..7
    const int p  = lane & 7;
    const char* gsrc = nullptr; const char* usrc = nullptr;
    // fp32 fallback staging coords
    const int sr = tid >> 1;    // 0..127
    const int sh = tid & 1;
    const float* gF = nullptr; const float* uF = nullptr;
    if (WB) {
        const ushort* wgp = (const ushort*)wgate_;
        const ushort* wup = (const ushort*)wup_;
        const size_t rowi = (size_t)e * H2 + (size_t)(ch * 128 + w * 32 + rr);
        gsrc = (const char*)(wgp + rowi * H) + ((p ^ rr) << 4);
        usrc = (const char*)(wup + rowi * H) + ((p ^ rr) << 4);
    } else {
        gF = (const float*)wgate_ + ((size_t)e * H2 + (size_t)(ch * 128 + sr)) * H;
        uF = (const float*)wup_   + ((size_t)e * H2 + (size_t)(ch * 128 + sr)) * H;
    }

    f32x4 accg[8], accu[8];
    const f32x4 fz = {0.f, 0.f, 0.f, 0.f};
#pragma unroll
    for (int ni = 0; ni < 8; ++ni) { accg[ni] = fz; accu[ni] = fz; }

    // A prefetch for iter 0
    uint4 a0 = *(const uint4*)(aptr + quad * 16);
    uint4 a1 = *(const uint4*)(aptr + 64 + quad * 16);

    for (int it = 0; it < 8; ++it) {
        __syncthreads();   // prior iter's LDS reads done before overwrite
        if (WB) {
#pragma unroll
            for (int i = 0; i < 4; ++i) {
                dma16(gsrc + i * (8 * H * 2), (char*)Gs + w * 4096 + i * 1024);
                dma16(usrc + i * (8 * H * 2), (char*)Us + w * 4096 + i * 1024);
            }
        } else {
#pragma unroll
            for (int i = 0; i < 4; ++i) {
                const int pslot = sh * 4 + i;
                const int pc = pslot ^ (sr & 7);
                const float4* s1 = (const float4*)(gF + it * 64 + pc * 8);
                float4 g0 = s1[0], g1 = s1[1];
                uint4 v;
                v.x = pack_bf16(g0.x, g0.y); v.y = pack_bf16(g0.z, g0.w);
                v.z = pack_bf16(g1.x, g1.y); v.w = pack_bf16(g1.z, g1.w);
                ((uint4*)Gs)[sr * 8 + pslot] = v;
                const float4* s2 = (const float4*)(uF + it * 64 + pc * 8);
                float4 u0 = s2[0], u1 = s2[1];
                uint4 q;
                q.x = pack_bf16(u0.x, u0.y); q.y = pack_bf16(u0.z, u0.w);
                q.z = pack_bf16(u1.x, u1.y); q.w = pack_bf16(u1.z, u1.w);
                ((uint4*)Us)[sr * 8 + pslot] = q;
            }
        }
        // A prefetch next iter
        const int itn = (it < 7) ? it + 1 : 7;
        uint4 an0 = *(const uint4*)(aptr + itn * 128 + quad * 16);
        uint4 an1 = *(const uint4*)(aptr + itn * 128 + 64 + quad * 16);
        __syncthreads();   // drains DMA (vmcnt0) + LDS writes visible

#pragma unroll
        for (int ks = 0; ks < 2; ++ks) {
            bf16x8 af = ks ? *(bf16x8*)&a1 : *(bf16x8*)&a0;
#pragma unroll
            for (int ni = 0; ni < 8; ++ni) {
                const int n = ni * 16 + l15;
                const int slot = n * 8 + ((ks * 4 + quad) ^ (n & 7));
                bf16x8 bg = ((const bf16x8*)Gs)[slot];
                bf16x8 bu = ((const bf16x8*)Us)[slot];
                accg[ni] = __builtin_amdgcn_mfma_f32_16x16x32_bf16(af, bg, accg[ni], 0, 0, 0);
                accu[ni] = __builtin_amdgcn_mfma_f32_16x16x32_bf16(af, bu, accu[ni], 0, 0, 0);
            }
        }
        a0 = an0; a1 = an1;
        if (WB) { gsrc += 128; usrc += 128; }
    }

    // epilogue: hidden = silu(g)*u * w_pair -> LDS transpose -> coalesced store
    __syncthreads();
    ushort* T = smem;
#pragma unroll
    for (int r = 0; r < 4; ++r) {
        const int row = w * 16 + quad * 4 + r;
        const int slot2 = m0 + row;
        const float wgt = (slot2 < count) ? listW[e * CAP + slot2] : 0.f;
#pragma unroll
        for (int ni = 0; ni < 8; ++ni) {
            float gv = accg[ni][r], uv = accu[ni][r];
            float hv = (gv / (1.f + __expf(-gv))) * uv * wgt;
            T[row * TSTRIDE + ni * 16 + l15] = (ushort)bf16r(hv);
        }
    }
    __syncthreads();
    {
        const int row = tid >> 2;      // 0..63
        const int qp  = tid & 3;       // 4 threads/row x 4 uint4 = 256 B/row
        const int slot2 = m0 + row;
        if (slot2 < count) {
            const int pr = listPair[e * CAP + slot2];
            uint4* dst = (uint4*)(hidden + (size_t)pr * H2 + ch * 128) + qp * 4;
            const uint4* src = (const uint4*)(T + row * TSTRIDE) + qp * 4;
#pragma unroll
            for (int i = 0; i < 4; ++i) dst[i] = src[i];
        }
    }
}

// ---------------------------------------------------------------------------
// Kernel 3: grouped GEMM2: pairOut[ks2][pair][H-chunk] = hidden @ wd^T
// item = tile*8 + ks2*4 + ch.
// ---------------------------------------------------------------------------
template<bool WB>
__global__ __launch_bounds__(256, 4) void moe_gemm2(
    const void* __restrict__ wdown_, const ushort* __restrict__ hidden,
    const int* __restrict__ cnt, const int* __restrict__ listPair,
    ushort* __restrict__ pairOut,
    const int* __restrict__ ntiles, const int* __restrict__ desc)
{
    const int item = blockIdx.x;
    if (item >= (*ntiles) * 8) return;
    const int d   = desc[item >> 3];
    const int ks2 = (item >> 2) & 1;
    const int ch  = item & 3;
    const int e   = d >> 16;
    const int mt  = d & 0xffff;
    const int count = cnt[e];
    const int m0 = mt * BM;

    __shared__ ushort smem[9216];   // 18 KB: Bs (16 KB); epilogue T overlays
    ushort* Bs = smem;

    const int tid  = threadIdx.x;
    const int lane = tid & 63;
    const int w    = tid >> 6;
    const int l15  = lane & 15;
    const int quad = lane >> 4;

    const int arow = m0 + w * 16 + l15;
    const int apr  = (arow < count) ? listPair[e * CAP + arow] : 0;
    const char* aptr = (const char*)(hidden + (size_t)apr * H2 + ks2 * 512);

    const int rr = lane >> 3;
    const int p  = lane & 7;
    const char* bsrc = nullptr;
    const int sr = tid >> 1;
    const int sh = tid & 1;
    const float* bF = nullptr;
    if (WB) {
        const ushort* wdp = (const ushort*)wdown_;
        const size_t rowi = (size_t)e * H + (size_t)(ch * 128 + w * 32 + rr);
        bsrc = (const char*)(wdp + rowi * H2 + ks2 * 512) + ((p ^ rr) << 4);
    } else {
        bF = (const float*)wdown_ + ((size_t)e * H + (size_t)(ch * 128 + sr)) * H2 + ks2 * 512;
    }

    f32x4 acc[8];
    const f32x4 fz = {0.f, 0.f, 0.f, 0.f};
#pragma unroll
    for (int ni = 0; ni < 8; ++ni) acc[ni] = fz;

    uint4 a0 = *(const uint4*)(aptr + quad * 16);
    uint4 a1 = *(const uint4*)(aptr + 64 + quad * 16);

    for (int it = 0; it < 8; ++it) {
        __syncthreads();
        if (WB) {
#pragma unroll
            for (int i = 0; i < 4; ++i)
                dma16(bsrc + i * (8 * H2 * 2), (char*)Bs + w * 4096 + i * 1024);
        } else {
#pragma unroll
            for (int i = 0; i < 4; ++i) {
                const int pslot = sh * 4 + i;
                const int pc = pslot ^ (sr & 7);
                const float4* s1 = (const float4*)(bF + it * 64 + pc * 8);
                float4 b0 = s1[0], b1 = s1[1];
                uint4 v;
                v.x = pack_bf16(b0.x, b0.y); v.y = pack_bf16(b0.z, b0.w);
                v.z = pack_bf16(b1.x, b1.y); v.w = pack_bf16(b1.z, b1.w);
                ((uint4*)Bs)[sr * 8 + pslot] = v;
            }
        }
        const int itn = (it < 7) ? it + 1 : 7;
        uint4 an0 = *(const uint4*)(aptr + itn * 128 + quad * 16);
        uint4 an1 = *(const uint4*)(aptr + itn * 128 + 64 + quad * 16);
        __syncthreads();

#pragma unroll
        for (int ks = 0; ks < 2; ++ks) {
            bf16x8 af = ks ? *(bf16x8*)&a1 : *(bf16x8*)&a0;
#pragma unroll
            for (int ni = 0; ni < 8; ++ni) {
                const int n = ni * 16 + l15;
                const int slot = n * 8 + ((ks * 4 + quad) ^ (n & 7));
                bf16x8 bb = ((const bf16x8*)Bs)[slot];
                acc[ni] = __builtin_amdgcn_mfma_f32_16x16x32_bf16(af, bb, acc[ni], 0, 0, 0);
            }
        }
        a0 = an0; a1 = an1;
        if (WB) bsrc += 128;
    }

    // epilogue: transpose -> coalesced bf16 partial store
    __syncthreads();
    ushort* T = smem;
#pragma unroll
    for (int r = 0; r < 4; ++r) {
        const int row = w * 16 + quad * 4 + r;
#pragma unroll
        for (int ni = 0; ni < 8; ++ni)
            T[row * TSTRIDE + ni * 16 + l15] = (ushort)bf16r(acc[ni][r]);
    }
    __syncthreads();
    {
        const int row = tid >> 2;      // 0..63
        const int qp  = tid & 3;       // 4 threads/row x 4 uint4 = 256 B/row
        const int slot2 = m0 + row;
        if (slot2 < count) {
            const int pr = listPair[e * CAP + slot2];
            uint4* dst = (uint4*)(pairOut + ((size_t)(ks2 << 13) + pr) * H + ch * 128) + qp * 4;
            const uint4* src = (const uint4*)(T + row * TSTRIDE) + qp * 4;
#pragma unroll
            for (int i = 0; i < 4; ++i) dst[i] = src[i];
        }
    }
}

// ---------------------------------------------------------------------------
// Kernel 4: combine — out[t][c] = sum over k(4) x split(2). Overwrites d_out.
// ---------------------------------------------------------------------------
__global__ __launch_bounds__(256) void combine_kernel(
    const ushort* __restrict__ pairOut, float* __restrict__ out)
{
    const int tok = blockIdx.x * 4 + (threadIdx.x >> 6);
    const int c   = (threadIdx.x & 63) * 8;
    float s[8];
#pragma unroll
    for (int i = 0; i < 8; ++i) s[i] = 0.f;
#pragma unroll
    for (int j = 0; j < 8; ++j) {
        const int row = ((j >> 2) << 13) + tok * 4 + (j & 3);
        uint4 v = *(const uint4*)(pairOut + (size_t)row * H + c);
        const ushort* u = (const ushort*)&v;
#pragma unroll
        for (int i = 0; i < 8; ++i) s[i] += bf16f(u[i]);
    }
    float4* o = (float4*)(out + (size_t)tok * H + c);
    o[0] = make_float4(s[0], s[1], s[2], s[3]);
    o[1] = make_float4(s[4], s[5], s[6], s[7]);
}

// ---------------------------------------------------------------------------
extern "C" void kernel_launch(void* const* d_in, const int* in_sizes, int n_in,
                              void* d_out, int out_size, void* d_ws, size_t ws_size,
                              hipStream_t stream)
{
    (void)in_sizes; (void)n_in; (void)out_size;
    const float* x      = (const float*)d_in[0];
    const float* gate_w = (const float*)d_in[1];
    const float* w_gate = (const float*)d_in[2];
    const float* w_up   = (const float*)d_in[3];
    const float* w_down = (const float*)d_in[4];

    char* ws = (char*)d_ws;
    int* cnt    = (int*)ws;              // 128 B
    int* ntiles = (int*)(ws + 128);
    int* desc   = (int*)(ws + 256);      // MAXT64*4 = 640 B

    size_t off = 1024;
    int*    listTok  = (int*)(ws + off);   off += (size_t)NE * CAP * 4;
    int*    listPair = (int*)(ws + off);   off += (size_t)NE * CAP * 4;
    float*  listW    = (float*)(ws + off); off += (size_t)NE * CAP * 4;
    ushort* xbf      = (ushort*)(ws + off); off += (size_t)NTOK * H * 2;
    ushort* hidden   = (ushort*)(ws + off); off += (size_t)NTOK * 4 * H2 * 2;    // 16 MB
    ushort* pairOut  = (ushort*)(ws + off); off += (size_t)2 * NTOK * 4 * H * 2; // 16 MB
    ushort* wgb = (ushort*)(ws + off); off += (size_t)NE * H2 * H * 2;  // 32 MB
    ushort* wub = (ushort*)(ws + off); off += (size_t)NE * H2 * H * 2;  // 32 MB
    ushort* wdb = (ushort*)(ws + off); off += (size_t)NE * H * H2 * 2;  // 32 MB
    const size_t need_full = off;

    const bool full = (ws_size >= need_full);

    hipMemsetAsync(ws, 0, 256, stream);

    if (full) {
        prep_kernel<<<512 + 3 * 8192, 256, 0, stream>>>(
            x, gate_w, cnt, listTok, listPair, listW, xbf,
            w_gate, w_up, w_down, wgb, wub, wdb);
        sched_kernel<<<1, 64, 0, stream>>>(cnt, ntiles, desc);
        moe_gemm1<true><<<MAXT64 * 8, 256, 0, stream>>>(
            (const void*)wgb, (const void*)wub, xbf, cnt, listTok, listPair,
            listW, hidden, ntiles, desc);
        moe_gemm2<true><<<MAXT64 * 8, 256, 0, stream>>>(
            (const void*)wdb, hidden, cnt, listPair, pairOut, ntiles, desc);
    } else {
        prep_kernel<<<512, 256, 0, stream>>>(
            x, gate_w, cnt, listTok, listPair, listW, xbf,
            w_gate, w_up, w_down, nullptr, nullptr, nullptr);
        sched_kernel<<<1, 64, 0, stream>>>(cnt, ntiles, desc);
        moe_gemm1<false><<<MAXT64 * 8, 256, 0, stream>>>(
            (const void*)w_gate, (const void*)w_up, xbf, cnt, listTok, listPair,
            listW, hidden, ntiles, desc);
        moe_gemm2<false><<<MAXT64 * 8, 256, 0, stream>>>(
            (const void*)w_down, hidden, cnt, listPair, pairOut, ntiles, desc);
    }
    combine_kernel<<<NTOK / 4, 256, 0, stream>>>(pairOut, (float*)d_out);
}